// Round 4
// baseline (62.011 us; speedup 1.0000x reference)
//
#include <hip/hip_runtime.h>

// CorrelationAlign: out[b, a*63+c, i, j] = in[b, (a+i-31)*32 + (c+j-31), i, j]
//   valid iff 0 <= a+i-31 < 32 and 0 <= c+j-31 < 32, else 0.  b=16, h=w=32.
//
// Block = (b, a, i-group of 4). Wave w owns i = i0+w: loads its 32x32 input
// tile (32 contiguous 128B rows) into LDS, or zero-fills LDS if p invalid.
// One barrier per 4 tiles. Store phase: 63 c-rows x 512B contiguous spans
// (4 i's adjacent in output layout), float4 nontemporal stores.
// Per-tile LDS stride 1057 = 32*33+1: diagonal read bank = (c + 2j + isb) % 32
// -> <=2-way aliasing (free, m136).

typedef float f32x4 __attribute__((ext_vector_type(4)));

#define TSTR 1057   // per-i LDS tile stride (floats)

__global__ __launch_bounds__(256) void CorrelationAlign_kernel(
    const float* __restrict__ in, float* __restrict__ out) {
  __shared__ float tile[4 * TSTR];   // 16912 B -> 8 blocks/CU

  const int bid = blockIdx.x;        // ((b*63 + a) * 8 + g)
  const int g  = bid & 7;
  const int ba = bid >> 3;
  const int a  = ba % 63;
  const int b  = ba / 63;
  const int i0 = g * 4;
  const int t  = threadIdx.x;

  float* outbase = out + (size_t)(b * 3969 + a * 63) * 1024 + i0 * 32;

  const int plo = a + i0 - 31;                    // p for i_sub = 0
  const bool any_valid = (plo <= 31) && (plo + 3 >= 0);   // block-uniform

  if (any_valid) {
    const int w    = t >> 6;                      // wave id = i_sub
    const int lane = t & 63;
    const int p    = plo + w;
    if ((unsigned)p < 32u) {                      // wave-uniform branch
      const float* inptr =
          in + (size_t)(b * 1024 + p * 32) * 1024 + (i0 + w) * 32;
#pragma unroll
      for (int r = 0; r < 4; ++r) {
        const int idx = r * 64 + lane;
        const int q   = idx >> 3;
        const int j0  = (idx & 7) << 2;
        const f32x4 v = __builtin_nontemporal_load(
            reinterpret_cast<const f32x4*>(inptr + q * 1024 + j0));
        float* dst = &tile[w * TSTR + q * 33 + j0];
        dst[0] = v.x; dst[1] = v.y; dst[2] = v.z; dst[3] = v.w;
      }
    } else {
#pragma unroll
      for (int r = 0; r < 4; ++r) {
        const int idx = r * 64 + lane;
        const int q   = idx >> 3;
        const int j0  = (idx & 7) << 2;
        float* dst = &tile[w * TSTR + q * 33 + j0];
        dst[0] = 0.f; dst[1] = 0.f; dst[2] = 0.f; dst[3] = 0.f;
      }
    }
    __syncthreads();

    // 63 c-rows x 32 float4 (= 512B span over 4 i's) = 2016 tasks
    for (int task = t; task < 63 * 32; task += 256) {
      const int c   = task >> 5;
      const int wn  = task & 31;      // isb*8 + j0_idx
      const int isb = wn >> 3;
      const int j0  = (wn & 7) << 2;
      f32x4 v;
#pragma unroll
      for (int k = 0; k < 4; ++k) {
        const int j  = j0 + k;
        const int q  = c + j - 31;
        const int qc = min(max(q, 0), 31);
        const float x = tile[isb * TSTR + qc * 33 + j];
        v[k] = ((unsigned)q < 32u) ? x : 0.0f;
      }
      __builtin_nontemporal_store(
          v, reinterpret_cast<f32x4*>(outbase + (size_t)c * 1024 + wn * 4));
    }
  } else {
    // whole (c, i-group, j) plane is zero
    const f32x4 z = {0.f, 0.f, 0.f, 0.f};
    for (int task = t; task < 63 * 32; task += 256) {
      const int c  = task >> 5;
      const int wn = task & 31;
      __builtin_nontemporal_store(
          z, reinterpret_cast<f32x4*>(outbase + (size_t)c * 1024 + wn * 4));
    }
  }
}

extern "C" void kernel_launch(void* const* d_in, const int* in_sizes, int n_in,
                              void* d_out, int out_size, void* d_ws,
                              size_t ws_size, hipStream_t stream) {
  (void)in_sizes; (void)n_in; (void)out_size; (void)d_ws; (void)ws_size;
  const float* in = (const float*)d_in[0];
  float* out = (float*)d_out;
  const int grid = 16 * 63 * 8;   // one block per (b, a, i-group-of-4)
  CorrelationAlign_kernel<<<grid, 256, 0, stream>>>(in, out);
}